// Round 3
// baseline (250.637 us; speedup 1.0000x reference)
//
#include <hip/hip_runtime.h>
#include <math.h>

#define NB 4
#define NH 16
#define NCC 64
#define CSC 64
#define DC 64
#define S 72            // LDS row stride in bf16 elems
#define EPSF 1e-6f

typedef __attribute__((ext_vector_type(8))) short bf16x8;   // MFMA A/B frag (4 VGPR)
typedef __attribute__((ext_vector_type(4))) float f32x4;    // MFMA C/D frag
typedef __attribute__((ext_vector_type(4))) short short4v;

__device__ __forceinline__ short cvt_bf16(float x) {        // RNE f32->bf16
    union { float f; unsigned u; } v; v.f = x;
    unsigned r = v.u + 0x7fffu + ((v.u >> 16) & 1u);
    return (short)(r >> 16);
}
__device__ __forceinline__ float bf16_to_f(short s) {
    union { unsigned u; float f; } v; v.u = ((unsigned)(unsigned short)s) << 16;
    return v.f;
}
__device__ __forceinline__ float red16(float v) {           // sum over 16-lane group
    v += __shfl_xor(v, 1); v += __shfl_xor(v, 2);
    v += __shfl_xor(v, 4); v += __shfl_xor(v, 8);
    return v;
}

__global__ __launch_bounds__(1024, 1) void ttt_kernel(
    const float* __restrict__ xk, const float* __restrict__ xv,
    const float* __restrict__ weight, const float* __restrict__ bias,
    const float* __restrict__ gamma, const float* __restrict__ beta,
    const float* __restrict__ theta, const float* __restrict__ theta_bias,
    const float* __restrict__ alpha, float* __restrict__ out)
{
    __shared__ short xs_rm[CSC][S];   // xk chunk row-major (A of z/out)
    __shared__ short xsT [DC][S];     // xk chunk transposed (B of dW)
    __shared__ short gsT [DC][S];     // eta*grad_x transposed (A of dW)
    __shared__ short Wtb [DC][S];     // W^T bf16 (B of z/out)
    __shared__ float dbp [16][DC];    // per-wave db partials
    __shared__ float bs  [DC];        // bias state (fp32)

    const int t   = threadIdx.x;
    const int w   = t >> 6;           // wave 0..15
    const int l   = t & 63;
    const int g   = l >> 4;           // 16-lane group 0..3
    const int la  = l & 15;
    const int b2  = w >> 2;           // 16-row band 0..3
    const int sub = w & 3;            // redundancy index -> owned C-row i
    const int r   = 16 * b2 + 4 * g + sub;   // this thread's epilogue/output row
    const int bh  = blockIdx.x;
    const int h   = bh & (NH - 1);

    // per-col constants (cols 16n+la)
    float gam[4], bet[4], thv[4];
#pragma unroll
    for (int n = 0; n < 4; ++n) {
        gam[n] = gamma[h * DC + 16 * n + la];
        bet[n] = beta [h * DC + 16 * n + la];
        thv[n] = theta[h * DC + 16 * n + la];
    }
    const float tb  = theta_bias[h];
    const float tok = fmaxf(1.0f / (float)(r + 1) + alpha[r], 0.0f);

    // W state: wave (b2,sub) owns W^T rows [16b2,16b2+16) x cols [16sub,16sub+16)
    // thread holds Wreg[i] = W^T[16b2+4g+i][16sub+la] = W[16sub+la][16b2+4g+i]
    const float* wg = weight + h * DC * DC;
    float Wreg[4];
#pragma unroll
    for (int i = 0; i < 4; ++i)
        Wreg[i] = wg[(16 * sub + la) * DC + 16 * b2 + 4 * g + i];
#pragma unroll
    for (int i = 0; i < 4; ++i)
        Wtb[16 * b2 + 4 * g + i][16 * sub + la] = cvt_bf16(Wreg[i]);
    if (t < DC) bs[t] = bias[h * DC + t];

    const size_t bh_off = (size_t)bh * NCC * CSC * DC;
    const float* xkb = xk + bh_off;
    const float* xvb = xv + bh_off;
    float*       ob  = out + bh_off;

    float4 xl = ((const float4*)xkb)[t];   // prefetch chunk 0 (1 float4/thread)
    __syncthreads();                        // Wtb, bs ready

    for (int c = 0; c < NCC; ++c) {
        // ---- stage xs (row-major + transposed) ----
        {
            const int k = t >> 4, j = t & 15;
            short4v s4;
            s4[0] = cvt_bf16(xl.x); s4[1] = cvt_bf16(xl.y);
            s4[2] = cvt_bf16(xl.z); s4[3] = cvt_bf16(xl.w);
            *(short4v*)&xs_rm[k][4 * j] = s4;
            xsT[4 * j + 0][k] = s4[0]; xsT[4 * j + 1][k] = s4[1];
            xsT[4 * j + 2][k] = s4[2]; xsT[4 * j + 3][k] = s4[3];
        }
        __syncthreads();                    // sync1: xs visible

        // ---- z = xs @ W (band b2, redundant across sub) ----
        const bf16x8 a0 = *(const bf16x8*)&xs_rm[16 * b2 + la][8 * g];
        const bf16x8 a1 = *(const bf16x8*)&xs_rm[16 * b2 + la][8 * g + 32];
        f32x4 zt[4];
#pragma unroll
        for (int n = 0; n < 4; ++n) {
            bf16x8 b0 = *(const bf16x8*)&Wtb[16 * n + la][8 * g];
            bf16x8 b1 = *(const bf16x8*)&Wtb[16 * n + la][8 * g + 32];
            f32x4 zz = {0.f, 0.f, 0.f, 0.f};
            zz = __builtin_amdgcn_mfma_f32_16x16x32_bf16(a0, b0, zz, 0, 0, 0);
            zz = __builtin_amdgcn_mfma_f32_16x16x32_bf16(a1, b1, zz, 0, 0, 0);
            zt[n] = zz;
        }
        // extract owned row i=sub (wave-uniform branch)
        float zn[4];
        if      (sub == 0) { zn[0]=zt[0][0]; zn[1]=zt[1][0]; zn[2]=zt[2][0]; zn[3]=zt[3][0]; }
        else if (sub == 1) { zn[0]=zt[0][1]; zn[1]=zt[1][1]; zn[2]=zt[2][1]; zn[3]=zt[3][1]; }
        else if (sub == 2) { zn[0]=zt[0][2]; zn[1]=zt[1][2]; zn[2]=zt[2][2]; zn[3]=zt[3][2]; }
        else               { zn[0]=zt[0][3]; zn[1]=zt[1][3]; zn[2]=zt[2][3]; zn[3]=zt[3][3]; }

        // prefetch next chunk
        if (c + 1 < NCC) xl = ((const float4*)(xkb + (c + 1) * CSC * DC))[t];

        // ---- epilogue (1 row/thread) ----
        const float* xvc = xvb + c * CSC * DC;
        float xvf[4], xkcf[4], z[4];
#pragma unroll
        for (int n = 0; n < 4; ++n) {
            xvf[n]  = xvc[r * DC + 16 * n + la];
            xkcf[n] = bf16_to_f(xs_rm[r][16 * n + la]);
            z[n]    = zn[n] + bs[16 * n + la];
        }
        const float mu = red16(z[0] + z[1] + z[2] + z[3]) * (1.0f / DC);
        float d0 = z[0]-mu, d1 = z[1]-mu, d2 = z[2]-mu, d3 = z[3]-mu;
        const float var  = red16(d0*d0 + d1*d1 + d2*d2 + d3*d3) * (1.0f / DC);
        const float rstd = rsqrtf(var + EPSF);
        const float thd  = red16(xkcf[0]*thv[0] + xkcf[1]*thv[1] +
                                 xkcf[2]*thv[2] + xkcf[3]*thv[3]);
        const float lr   = 1.0f / (1.0f + expf(-(thd + tb)));
        const float eta  = tok * lr * (1.0f / DC);
        float dv[4] = {d0, d1, d2, d3};
        float xh[4], gxh[4], s1 = 0.f, s2 = 0.f;
#pragma unroll
        for (int n = 0; n < 4; ++n) {
            xh[n] = dv[n] * rstd;
            float y  = fmaf(gam[n], xh[n], bet[n]);
            float go = y - xvf[n] + xkcf[n];
            gxh[n] = go * gam[n];
            s1 += gxh[n];
            s2 = fmaf(gxh[n], xh[n], s2);
        }
        s1 = red16(s1); s2 = red16(s2);
        const float sc = rstd * (1.0f / DC) * eta;
        float gsv[4], dbl[4];
#pragma unroll
        for (int n = 0; n < 4; ++n) {
            gsv[n] = (64.0f * gxh[n] - s1 - xh[n] * s2) * sc;
            gsT[16 * n + la][r] = cvt_bf16(gsv[n]);
            float dd = gsv[n];
            dd += __shfl_xor(dd, 16);       // sum over g (wave's 4 rows)
            dd += __shfl_xor(dd, 32);
            dbl[n] = dd;
        }
        if (l < 16) {
#pragma unroll
            for (int n = 0; n < 4; ++n) dbp[w][16 * n + la] = dbl[n];
        }
        __syncthreads();                    // sync2: gsT, dbp ready

        // ---- dW^T tile (b2, sub): 2 MFMA; state update in regs ----
        {
            bf16x8 ag0 = *(const bf16x8*)&gsT[16 * b2 + la][8 * g];
            bf16x8 ag1 = *(const bf16x8*)&gsT[16 * b2 + la][8 * g + 32];
            bf16x8 bx0 = *(const bf16x8*)&xsT[16 * sub + la][8 * g];
            bf16x8 bx1 = *(const bf16x8*)&xsT[16 * sub + la][8 * g + 32];
            f32x4 dw = {0.f, 0.f, 0.f, 0.f};
            dw = __builtin_amdgcn_mfma_f32_16x16x32_bf16(ag0, bx0, dw, 0, 0, 0);
            dw = __builtin_amdgcn_mfma_f32_16x16x32_bf16(ag1, bx1, dw, 0, 0, 0);
#pragma unroll
            for (int i = 0; i < 4; ++i) {
                Wreg[i] -= dw[i];
                Wtb[16 * b2 + 4 * g + i][16 * sub + la] = cvt_bf16(Wreg[i]);
            }
        }
        if (w == 0) {                       // bias state update, fixed-order sum
            float db = 0.f;
#pragma unroll
            for (int p = 0; p < 16; ++p) db += dbp[p][l];
            bs[l] -= db;
        }
        __syncthreads();                    // sync3: Wtb, bs updated

        // ---- out = xs @ Wn + bn (band b2, redundant; store own row) ----
        float* oc = ob + c * CSC * DC;
        f32x4 ot[4];
#pragma unroll
        for (int n = 0; n < 4; ++n) {
            bf16x8 b0 = *(const bf16x8*)&Wtb[16 * n + la][8 * g];
            bf16x8 b1 = *(const bf16x8*)&Wtb[16 * n + la][8 * g + 32];
            f32x4 oz = {0.f, 0.f, 0.f, 0.f};
            oz = __builtin_amdgcn_mfma_f32_16x16x32_bf16(a0, b0, oz, 0, 0, 0);
            oz = __builtin_amdgcn_mfma_f32_16x16x32_bf16(a1, b1, oz, 0, 0, 0);
            ot[n] = oz;
        }
        float on[4];
        if      (sub == 0) { on[0]=ot[0][0]; on[1]=ot[1][0]; on[2]=ot[2][0]; on[3]=ot[3][0]; }
        else if (sub == 1) { on[0]=ot[0][1]; on[1]=ot[1][1]; on[2]=ot[2][1]; on[3]=ot[3][1]; }
        else if (sub == 2) { on[0]=ot[0][2]; on[1]=ot[1][2]; on[2]=ot[2][2]; on[3]=ot[3][2]; }
        else               { on[0]=ot[0][3]; on[1]=ot[1][3]; on[2]=ot[2][3]; on[3]=ot[3][3]; }
#pragma unroll
        for (int n = 0; n < 4; ++n)
            oc[r * DC + 16 * n + la] = on[n] + bs[16 * n + la];
    }
}

extern "C" void kernel_launch(void* const* d_in, const int* in_sizes, int n_in,
                              void* d_out, int out_size, void* d_ws, size_t ws_size,
                              hipStream_t stream) {
    const float* xk         = (const float*)d_in[0];
    const float* xv         = (const float*)d_in[1];
    const float* weight     = (const float*)d_in[2];
    const float* bias       = (const float*)d_in[3];
    const float* gamma      = (const float*)d_in[4];
    const float* beta       = (const float*)d_in[5];
    const float* theta      = (const float*)d_in[6];
    const float* theta_bias = (const float*)d_in[7];
    const float* alpha      = (const float*)d_in[8];
    float* out = (float*)d_out;

    ttt_kernel<<<NB * NH, 1024, 0, stream>>>(xk, xv, weight, bias, gamma, beta,
                                             theta, theta_bias, alpha, out);
}

// Round 4
// 249.766 us; speedup vs baseline: 1.0035x; 1.0035x over previous
//
#include <hip/hip_runtime.h>
#include <math.h>

#define NB 4
#define NH 16
#define NCC 64
#define CSC 64
#define DC 64
#define S 72            // LDS row stride (bf16): 144B rows, stride 36 words ≡ 4 mod 32 banks (uniform)
#define EPSF 1e-6f

typedef __attribute__((ext_vector_type(8))) short bf16x8;   // MFMA A/B frag (4 VGPR)
typedef __attribute__((ext_vector_type(4))) float f32x4;    // MFMA C/D frag
typedef __attribute__((ext_vector_type(4))) short short4v;

static __device__ __forceinline__ short cvt_bf16(float x) { // RNE f32->bf16
    union { float f; unsigned u; } v; v.f = x;
    unsigned r = v.u + 0x7fffu + ((v.u >> 16) & 1u);
    return (short)(r >> 16);
}
static __device__ __forceinline__ float red16(float v) {    // sum over 16-lane group
    v += __shfl_xor(v, 1); v += __shfl_xor(v, 2);
    v += __shfl_xor(v, 4); v += __shfl_xor(v, 8);
    return v;
}

__global__ __launch_bounds__(256, 1) void ttt_kernel(
    const float* __restrict__ xk, const float* __restrict__ xv,
    const float* __restrict__ weight, const float* __restrict__ bias,
    const float* __restrict__ gamma, const float* __restrict__ beta,
    const float* __restrict__ theta, const float* __restrict__ theta_bias,
    const float* __restrict__ alpha, float* __restrict__ out)
{
    __shared__ short xs_rm[2][CSC][S]; // xk chunk row-major (A of z/Gram, B of Gram)
    __shared__ short xsT [2][DC][S];   // xk chunk transposed [d][k] (A of dW)
    __shared__ short gsT [DC][S];      // gs transposed [e][k] (B of dW AND B of out)
    __shared__ short Gr  [CSC][S];     // Gram [j][k] (A of out), written via symmetry
    __shared__ short Wtb [DC][S];      // W stored [e][d] (B of z)
    __shared__ float dbp [4][DC];      // db partials, interleaved [w][4*la+n]

    const int t  = threadIdx.x;
    const int w  = t >> 6;            // wave 0..3
    const int l  = t & 63;
    const int g  = l >> 4;            // 16-lane group
    const int la = l & 15;
    const int bh = blockIdx.x;        // 0..63
    const int h  = bh & (NH - 1);
    const int r0 = 16 * w + 4 * g;    // first owned row (chunk-row / d-row)

    // per-col constants (cols e_n = 16n+la)
    float gam[4], bet[4], thv[4], bcol[4];
#pragma unroll
    for (int n = 0; n < 4; ++n) {
        gam[n]  = gamma[h*DC + 16*n + la];
        bet[n]  = beta [h*DC + 16*n + la];
        thv[n]  = theta[h*DC + 16*n + la];
        bcol[n] = bias [h*DC + 16*n + la];
    }
    const float tb = theta_bias[h];
    float tok[4];
#pragma unroll
    for (int i = 0; i < 4; ++i)
        tok[i] = fmaxf(1.0f/(float)(r0+i+1) + alpha[r0+i], 0.0f);

    // W state in regs: Wreg[i][n] = W[r0+i][16n+la]  (dW C-frag layout, [d][e])
    float Wreg[4][4];
    const float* wg = weight + h*DC*DC;
#pragma unroll
    for (int i = 0; i < 4; ++i)
#pragma unroll
        for (int n = 0; n < 4; ++n)
            Wreg[i][n] = wg[(r0+i)*DC + 16*n + la];
#pragma unroll
    for (int n = 0; n < 4; ++n) {                 // Wtb[e][d]: d=r0+i contiguous -> b64
        short4v sv;
#pragma unroll
        for (int i = 0; i < 4; ++i) sv[i] = cvt_bf16(Wreg[i][n]);
        *(short4v*)&Wtb[16*n + la][r0] = sv;
    }

    const size_t bh_off = (size_t)bh * NCC*CSC*DC;
    const float* xkb = xk + bh_off;
    const float* xvb = xv + bh_off;
    float*       ob  = out + bh_off;

    // chunk-0 staging + fp32 row data
    float4 xl[4];
#pragma unroll
    for (int i4 = 0; i4 < 4; ++i4) xl[i4] = ((const float4*)xkb)[t + 256*i4];
    float xkg[4][4], xvg[4][4];
#pragma unroll
    for (int i = 0; i < 4; ++i)
#pragma unroll
        for (int n = 0; n < 4; ++n) {
            xkg[i][n] = xkb[(r0+i)*DC + 16*n + la];
            xvg[i][n] = xvb[(r0+i)*DC + 16*n + la];
        }
#pragma unroll
    for (int i4 = 0; i4 < 4; ++i4) {
        int f = t + 256*i4, k = f >> 4, j = f & 15;
        short4v s4;
        s4[0]=cvt_bf16(xl[i4].x); s4[1]=cvt_bf16(xl[i4].y);
        s4[2]=cvt_bf16(xl[i4].z); s4[3]=cvt_bf16(xl[i4].w);
        *(short4v*)&xs_rm[0][k][4*j] = s4;
        xsT[0][4*j+0][k]=s4[0]; xsT[0][4*j+1][k]=s4[1];
        xsT[0][4*j+2][k]=s4[2]; xsT[0][4*j+3][k]=s4[3];
    }
    __syncthreads();

    for (int c = 0; c < NCC; ++c) {
        const int cb = c & 1;
        // prefetch next chunk's staging float4s (consumed end of P2)
        if (c + 1 < NCC) {
            const float* xkn = xkb + (c+1)*CSC*DC;
#pragma unroll
            for (int i4 = 0; i4 < 4; ++i4) xl[i4] = ((const float4*)xkn)[t + 256*i4];
        }

        // ---- P1: Gram + z MFMAs ----
        const bf16x8 aw0 = *(const bf16x8*)&xs_rm[cb][16*w + la][8*g];
        const bf16x8 aw1 = *(const bf16x8*)&xs_rm[cb][16*w + la][32 + 8*g];
        f32x4 zt[4], Cg[4];
#pragma unroll
        for (int n = 0; n < 4; ++n) {
            bf16x8 b0 = *(const bf16x8*)&xs_rm[cb][16*n + la][8*g];
            bf16x8 b1 = *(const bf16x8*)&xs_rm[cb][16*n + la][32 + 8*g];
            f32x4 cc = {0.f,0.f,0.f,0.f};
            cc = __builtin_amdgcn_mfma_f32_16x16x32_bf16(aw0, b0, cc, 0,0,0);
            cc = __builtin_amdgcn_mfma_f32_16x16x32_bf16(aw1, b1, cc, 0,0,0);
            Cg[n] = cc;                             // Gram[r0+i][16n+la]
            bf16x8 w0 = *(const bf16x8*)&Wtb[16*n + la][8*g];
            bf16x8 w1 = *(const bf16x8*)&Wtb[16*n + la][32 + 8*g];
            f32x4 zz = {0.f,0.f,0.f,0.f};
            zz = __builtin_amdgcn_mfma_f32_16x16x32_bf16(aw0, w0, zz, 0,0,0);
            zz = __builtin_amdgcn_mfma_f32_16x16x32_bf16(aw1, w1, zz, 0,0,0);
            zt[n] = zz;                             // z[r0+i][16n+la] (pre-bias)
        }
        // Gram write via symmetry: Gr[16n+la][r0+i] = Gram[r0+i][16n+la], i contiguous
#pragma unroll
        for (int n = 0; n < 4; ++n) {
            short4v sg;
#pragma unroll
            for (int i = 0; i < 4; ++i) sg[i] = cvt_bf16(Cg[n][i]);
            *(short4v*)&Gr[16*n + la][r0] = sg;
        }

        // ---- epilogue (fp32, 4 rows/thread, parallel reductions) ----
        float gsv[4][4];
#pragma unroll
        for (int i = 0; i < 4; ++i) {
            float z0 = zt[0][i]+bcol[0], z1 = zt[1][i]+bcol[1];
            float z2 = zt[2][i]+bcol[2], z3 = zt[3][i]+bcol[3];
            float szz = red16(z0*z0 + z1*z1 + z2*z2 + z3*z3);
            float sz  = red16(z0 + z1 + z2 + z3);
            float thd = red16(xkg[i][0]*thv[0] + xkg[i][1]*thv[1] +
                              xkg[i][2]*thv[2] + xkg[i][3]*thv[3]);
            float mu  = sz * (1.0f/DC);
            float var = szz*(1.0f/DC) - mu*mu;
            float rstd = rsqrtf(var + EPSF);
            float lr  = 1.0f/(1.0f + expf(-(thd + tb)));
            float eta = tok[i]*lr*(1.0f/DC);
            float zz4[4] = {z0,z1,z2,z3};
            float xh[4], gxh[4], a1v = 0.f, a2v = 0.f;
#pragma unroll
            for (int n = 0; n < 4; ++n) {
                xh[n] = (zz4[n]-mu)*rstd;
                float y  = fmaf(gam[n], xh[n], bet[n]);
                float go = y - xvg[i][n] + xkg[i][n];
                gxh[n] = go*gam[n];
                a1v += gxh[n];
                a2v = fmaf(gxh[n], xh[n], a2v);
            }
            float s1 = red16(a1v), s2 = red16(a2v);
            float sc = rstd*(1.0f/DC)*eta;
#pragma unroll
            for (int n = 0; n < 4; ++n)
                gsv[i][n] = (64.f*gxh[n] - s1 - xh[n]*s2)*sc;
        }
#pragma unroll
        for (int n = 0; n < 4; ++n) {               // gsT[e][k]: k=r0+i contiguous -> b64
            short4v sg;
#pragma unroll
            for (int i = 0; i < 4; ++i) sg[i] = cvt_bf16(gsv[i][n]);
            *(short4v*)&gsT[16*n + la][r0] = sg;
        }
        float dbl[4];
#pragma unroll
        for (int n = 0; n < 4; ++n) {
            float dd = gsv[0][n]+gsv[1][n]+gsv[2][n]+gsv[3][n];
            dd += __shfl_xor(dd, 16);
            dd += __shfl_xor(dd, 32);
            dbl[n] = dd;
        }
        if (l < 16) {
            f32x4 dv = {dbl[0], dbl[1], dbl[2], dbl[3]};
            *(f32x4*)&dbp[w][4*la] = dv;
        }
        __syncthreads();   // sync2: gsT, Gr, dbp ready; Wtb reads done

        // ---- P2 ----
        float xkgN[4][4], xvgN[4][4];
        if (c + 1 < NCC) {                          // prefetch fp32 rows (L2-hot xk, xv)
            const float* xkn = xkb + (c+1)*CSC*DC;
            const float* xvn = xvb + (c+1)*CSC*DC;
#pragma unroll
            for (int i = 0; i < 4; ++i)
#pragma unroll
                for (int n = 0; n < 4; ++n) {
                    xkgN[i][n] = xkn[(r0+i)*DC + 16*n + la];
                    xvgN[i][n] = xvn[(r0+i)*DC + 16*n + la];
                }
        }

        const bf16x8 ax0 = *(const bf16x8*)&xsT[cb][16*w + la][8*g];
        const bf16x8 ax1 = *(const bf16x8*)&xsT[cb][16*w + la][32 + 8*g];
        const bf16x8 ar0 = *(const bf16x8*)&Gr[16*w + la][8*g];
        const bf16x8 ar1 = *(const bf16x8*)&Gr[16*w + la][32 + 8*g];
        f32x4 outv[4];
#pragma unroll
        for (int n = 0; n < 4; ++n) {
            bf16x8 q0 = *(const bf16x8*)&gsT[16*n + la][8*g];      // shared B-frag
            bf16x8 q1 = *(const bf16x8*)&gsT[16*n + la][32 + 8*g];
            f32x4 dw = {0.f,0.f,0.f,0.f};                          // dW[d][e]
            dw = __builtin_amdgcn_mfma_f32_16x16x32_bf16(ax0, q0, dw, 0,0,0);
            dw = __builtin_amdgcn_mfma_f32_16x16x32_bf16(ax1, q1, dw, 0,0,0);
#pragma unroll
            for (int i = 0; i < 4; ++i) Wreg[i][n] -= dw[i];
            f32x4 og = {0.f,0.f,0.f,0.f};                          // (Gram@gs)[j][e]
            og = __builtin_amdgcn_mfma_f32_16x16x32_bf16(ar0, q0, og, 0,0,0);
            og = __builtin_amdgcn_mfma_f32_16x16x32_bf16(ar1, q1, og, 0,0,0);
            outv[n] = og;
        }
#pragma unroll
        for (int n = 0; n < 4; ++n) {               // new W -> Wtb (b64 packed)
            short4v sw;
#pragma unroll
            for (int i = 0; i < 4; ++i) sw[i] = cvt_bf16(Wreg[i][n]);
            *(short4v*)&Wtb[16*n + la][r0] = sw;
        }
        {   // bias state update (fixed order, identical across waves)
            f32x4 d0v = *(const f32x4*)&dbp[0][4*la];
            f32x4 d1v = *(const f32x4*)&dbp[1][4*la];
            f32x4 d2v = *(const f32x4*)&dbp[2][4*la];
            f32x4 d3v = *(const f32x4*)&dbp[3][4*la];
#pragma unroll
            for (int n = 0; n < 4; ++n)
                bcol[n] -= d0v[n] + d1v[n] + d2v[n] + d3v[n];
        }
        // out = z + b_old - Gram@gs - db = zt - outv + bcol_new
        float* oc = ob + c*CSC*DC;
#pragma unroll
        for (int i = 0; i < 4; ++i)
#pragma unroll
            for (int n = 0; n < 4; ++n)
                oc[(r0+i)*DC + 16*n + la] = zt[n][i] - outv[n][i] + bcol[n];

        // stage chunk c+1 into other buffer (overlaps with this phase)
        if (c + 1 < NCC) {
            const int nbuf = cb ^ 1;
#pragma unroll
            for (int i4 = 0; i4 < 4; ++i4) {
                int f = t + 256*i4, k = f >> 4, j = f & 15;
                short4v s4;
                s4[0]=cvt_bf16(xl[i4].x); s4[1]=cvt_bf16(xl[i4].y);
                s4[2]=cvt_bf16(xl[i4].z); s4[3]=cvt_bf16(xl[i4].w);
                *(short4v*)&xs_rm[nbuf][k][4*j] = s4;
                xsT[nbuf][4*j+0][k]=s4[0]; xsT[nbuf][4*j+1][k]=s4[1];
                xsT[nbuf][4*j+2][k]=s4[2]; xsT[nbuf][4*j+3][k]=s4[3];
            }
#pragma unroll
            for (int i = 0; i < 4; ++i)
#pragma unroll
                for (int n = 0; n < 4; ++n) {
                    xkg[i][n] = xkgN[i][n];
                    xvg[i][n] = xvgN[i][n];
                }
        }
        __syncthreads();   // sync3: Wtb + staged xs ready for next P1
    }
}

extern "C" void kernel_launch(void* const* d_in, const int* in_sizes, int n_in,
                              void* d_out, int out_size, void* d_ws, size_t ws_size,
                              hipStream_t stream) {
    const float* xk         = (const float*)d_in[0];
    const float* xv         = (const float*)d_in[1];
    const float* weight     = (const float*)d_in[2];
    const float* bias       = (const float*)d_in[3];
    const float* gamma      = (const float*)d_in[4];
    const float* beta       = (const float*)d_in[5];
    const float* theta      = (const float*)d_in[6];
    const float* theta_bias = (const float*)d_in[7];
    const float* alpha      = (const float*)d_in[8];
    float* out = (float*)d_out;

    ttt_kernel<<<NB * NH, 256, 0, stream>>>(xk, xv, weight, bias, gamma, beta,
                                            theta, theta_bias, alpha, out);
}